// Round 7
// baseline (72.020 us; speedup 1.0000x reference)
//
#include <hip/hip_runtime.h>
#include <hip/hip_bf16.h>
#include <stdint.h>

#define NB  256     // batch
#define NSP 128     // n_spins
#define DM  768     // d_model
#define KMC 25      // coalitions
#define MROWS (NB*KMC)  // 6400

// workspace layout (bytes), all 256-aligned (ws is 384 MiB)
#define OFF_S    0u          // s bf16 [6400][768]          9,830,400 B
#define OFF_WT   9830400u    // w_v^T bf16 [768][768]       1,179,648 B
#define OFF_N2   11010048u   // norm2 f32 [6400]               25,600 B
#define OFF_COEF 11035648u   // coefT f32 [128][28]            14,336 B
#define OFF_CB   11049984u   // Cb bf16 [32][128] (pad rows)    8,192 B

typedef __attribute__((ext_vector_type(8))) short bf16x8;
typedef __attribute__((ext_vector_type(4))) float f32x4;
typedef unsigned int u32;

#define GLOAD_LDS16(gp, lp) \
  __builtin_amdgcn_global_load_lds((const __attribute__((address_space(1))) u32*)(gp), \
                                   (__attribute__((address_space(3))) u32*)(lp), 16, 0, 0)

// ---------------- prep: transpose w_v -> bf16 wT, coef/C tables, zero norm2 -
__global__ __launch_bounds__(256) void prep_kernel(const float* __restrict__ wv,
                                                   const int* __restrict__ co,
                                                   char* __restrict__ ws) {
  const int blk = blockIdx.x;
  const int t = threadIdx.x;
  if (blk < 144) {               // 12x12 tiles of 64x64: wT[n][k] = bf16(wv[k][n])
    __shared__ __hip_bfloat16 lt[64][66];
    const int bi = blk / 12, bj = blk % 12;
    const int k0 = bi * 64, n0 = bj * 64;
    #pragma unroll
    for (int i = 0; i < 16; ++i) {
      int idx = t + i * 256;
      int r = idx >> 6, c = idx & 63;
      lt[c][r] = __float2bfloat16(wv[(size_t)(k0 + r) * DM + n0 + c]);
    }
    __syncthreads();
    __hip_bfloat16* wT = (__hip_bfloat16*)(ws + OFF_WT);
    #pragma unroll
    for (int i = 0; i < 16; ++i) {
      int idx = t + i * 256;
      int r = idx >> 6, c = idx & 63;
      wT[(size_t)(n0 + r) * DM + k0 + c] = lt[r][c];
    }
  } else if (blk == 144) {       // per-(n,k) shapley coefficients
    if (t < NSP) {
      const int n = t;
      int cw = 0;
      #pragma unroll
      for (int k = 0; k < KMC; ++k) cw += co[k * NSP + n];
      const int cwo = KMC - cw;
      const bool valid = (cw > 0) && (cwo > 0);
      float* coefT = (float*)(ws + OFF_COEF);
      #pragma unroll
      for (int k = 0; k < 28; ++k) {
        float v = 0.f;
        if (valid && k < KMC) v = co[k * NSP + n] ? (1.f / (float)cw) : (-1.f / (float)cwo);
        coefT[n * 28 + k] = v;
      }
    }
  } else if (blk < 170) {        // zero norm2 accumulators
    int i = (blk - 145) * 256 + t;
    if (i < MROWS) ((float*)(ws + OFF_N2))[i] = 0.f;
  } else {                       // blk 170..201: Cb row k (bf16, rows>=KMC zero)
    int k = blk - 170;
    if (t < NSP) {
      float v = (k < KMC) ? (float)co[k * NSP + t] : 0.f;
      ((__hip_bfloat16*)(ws + OFF_CB))[k * NSP + t] = __float2bfloat16(v);
    }
  }
}

// ---------------- kernel A: s[b] = C(25x128) x F_b(128x768) via bf16 MFMA ---
// 1 block/CU (grid 256 b x 2 halves, 512 thr = 8 waves, 48 cols/wave -> ct<3).
// F staged via regs (float2 loads issued early, ds_write_b64 late) into a
// double-buffered padded f32 slab [32][390] -> frag reads 2-way-bank (free).
#define KAPW 390            // padded slab row width (floats)
#define KASL (32 * KAPW)    // floats per buffer

__global__ __launch_bounds__(512, 2) void kA(const float* __restrict__ f,
                                             const __hip_bfloat16* __restrict__ Cb,
                                             __hip_bfloat16* __restrict__ s) {
  const int b = blockIdx.x;
  const int half = blockIdx.y;     // d-half: cols [half*384, half*384+384)
  const int tid = threadIdx.x;
  const int w = tid >> 6;          // 8 waves, 48 cols each
  const int lo = tid & 15, hi = (tid & 63) >> 4;

  __shared__ __align__(16) float Fs[2][KASL];   // 99,840 B

  // A-fragments (coalition rows), k = ks*32 + hi*8 + j (proven mapping)
  bf16x8 A0[4], A1[4];
  #pragma unroll
  for (int ks = 0; ks < 4; ++ks) {
    A0[ks] = *(const bf16x8*)(Cb + (size_t)lo * NSP + ks * 32 + hi * 8);
    A1[ks] = *(const bf16x8*)(Cb + (size_t)(16 + lo) * NSP + ks * 32 + hi * 8);
  }

  // per-thread staging geometry: 12 float2 per chunk, full-row coalesced
  int goff[12], waddr[12];
  #pragma unroll
  for (int p = 0; p < 12; ++p) {
    int e = 2 * tid + 1024 * p;        // float index into [32][384] slab
    int r = e / 384, c = e - r * 384;  // e even -> c even -> 8B-aligned LDS
    goff[p] = r * DM + c;
    waddr[p] = r * KAPW + c;
  }

  const float* fb = f + (size_t)b * NSP * DM + half * 384;

  f32x4 ac0[3], ac1[3];
  #pragma unroll
  for (int ct = 0; ct < 3; ++ct)
    #pragma unroll
    for (int i = 0; i < 4; ++i) { ac0[ct][i] = 0.f; ac1[ct][i] = 0.f; }

  float2 rA[12], rB[12];

#define KAL(chunk, reg) { \
    const float* fp_ = fb + (chunk) * 32 * DM; \
    _Pragma("unroll") for (int p = 0; p < 12; ++p) \
      reg[p] = *(const float2*)(fp_ + goff[p]); }

#define KAST(reg, bi) { \
    _Pragma("unroll") for (int p = 0; p < 12; ++p) \
      *(float2*)(&Fs[bi][waddr[p]]) = reg[p]; }

#define KAC(ks, bi) { \
    _Pragma("unroll") for (int ct = 0; ct < 3; ++ct) { \
      bf16x8 Bf; \
      _Pragma("unroll") for (int j = 0; j < 8; ++j) { \
        float v_ = Fs[bi][(hi * 8 + j) * KAPW + w * 48 + ct * 16 + lo]; \
        __hip_bfloat16 h_ = __float2bfloat16(v_); \
        Bf[j] = *(short*)&h_; } \
      ac0[ct] = __builtin_amdgcn_mfma_f32_16x16x32_bf16(A0[ks], Bf, ac0[ct], 0, 0, 0); \
      ac1[ct] = __builtin_amdgcn_mfma_f32_16x16x32_bf16(A1[ks], Bf, ac1[ct], 0, 0, 0); } }

  KAL(0, rA)
  KAL(1, rB)
  KAST(rA, 0)                    // waits rA only (rB stays in flight)
  __syncthreads();

  KAC(0, 0)
  __syncthreads();
  KAL(2, rA)                     // issue before the rB vmcnt-wait
  KAST(rB, 1)
  __syncthreads();

  KAC(1, 1)
  __syncthreads();
  KAL(3, rB)
  KAST(rA, 0)
  __syncthreads();

  KAC(2, 0)
  __syncthreads();
  KAST(rB, 1)
  __syncthreads();

  KAC(3, 1)

#undef KAL
#undef KAST
#undef KAC

  // epilogue: D layout col=lane&15, row=(lane>>4)*4+i
  #pragma unroll
  for (int ct = 0; ct < 3; ++ct) {
    int dcol = half * 384 + w * 48 + ct * 16 + lo;
    #pragma unroll
    for (int i = 0; i < 4; ++i) {
      int r0 = hi * 4 + i;
      s[((size_t)b * KMC + r0) * DM + dcol] = __float2bfloat16(ac0[ct][i]);
      int r1 = 16 + hi * 4 + i;
      if (r1 < KMC)
        s[((size_t)b * KMC + r1) * DM + dcol] = __float2bfloat16(ac1[ct][i]);
    }
  }
}

// ---------------- kernel B: norm2[row] += rowwise |s @ wT^T|^2 (bf16 MFMA) ---
#define BM 128
#define BN 192
#define BK 32
#define NTK 24   // 768/32

__global__ __launch_bounds__(256) void kB(char* __restrict__ ws) {
  const int bid = blockIdx.x;      // grid 200 = 50 (M) * 4 (N)
  const int tm = bid >> 2;
  const int tn = bid & 3;
  const int tid = threadIdx.x;
  const int wid = tid >> 6;
  const int lane = tid & 63;
  const int wm = wid >> 1;         // 2x2 wave grid: 64 rows x 96 cols per wave
  const int wn = wid & 1;

  const __hip_bfloat16* S  = (const __hip_bfloat16*)(ws + OFF_S);
  const __hip_bfloat16* WT = (const __hip_bfloat16*)(ws + OFF_WT);
  float* norm2 = (float*)(ws + OFF_N2);

  __shared__ __align__(16) char As[2][BM * BK * 2];  // [128][32] bf16, 64B rows
  __shared__ __align__(16) char Bs[2][BN * BK * 2];  // [192][32] bf16, 64B rows

  // staging: global src pre-swizzled (slot ^= (r>>1)&3), LDS dest linear
  const char* gA[2]; char *lA0[2], *lA1[2];
  #pragma unroll
  for (int j = 0; j < 2; ++j) {
    int li = (wid * 2 + j) * 64 + lane;
    int r = li >> 2, sl = li & 3;
    int slx = sl ^ ((r >> 1) & 3);
    gA[j] = (const char*)(S + (size_t)(tm * BM + r) * DM) + slx * 16;
    lA0[j] = As[0] + (wid * 2 + j) * 1024;
    lA1[j] = As[1] + (wid * 2 + j) * 1024;
  }
  const char* gB[3]; char *lB0[3], *lB1[3];
  #pragma unroll
  for (int j = 0; j < 3; ++j) {
    int li = (wid * 3 + j) * 64 + lane;
    int r = li >> 2, sl = li & 3;
    int slx = sl ^ ((r >> 1) & 3);
    gB[j] = (const char*)(WT + (size_t)(tn * BN + r) * DM) + slx * 16;
    lB0[j] = Bs[0] + (wid * 3 + j) * 1024;
    lB1[j] = Bs[1] + (wid * 3 + j) * 1024;
  }

  auto stage = [&](int tk, int bsel) {
    size_t koff = (size_t)tk * (BK * 2);   // 64 bytes per K-step
    #pragma unroll
    for (int j = 0; j < 2; ++j) GLOAD_LDS16(gA[j] + koff, bsel ? lA1[j] : lA0[j]);
    #pragma unroll
    for (int j = 0; j < 3; ++j) GLOAD_LDS16(gB[j] + koff, bsel ? lB1[j] : lB0[j]);
  };

  f32x4 acc[4][6];
  #pragma unroll
  for (int m = 0; m < 4; ++m)
    #pragma unroll
    for (int n = 0; n < 6; ++n)
      #pragma unroll
      for (int j = 0; j < 4; ++j) acc[m][n][j] = 0.f;

  // fragment read offsets (swizzled to match stage-source permutation)
  int offA[4], offB[6];
  #pragma unroll
  for (int m = 0; m < 4; ++m) {
    int r = wm * 64 + m * 16 + (lane & 15);
    int sl = (lane >> 4) ^ ((r >> 1) & 3);
    offA[m] = r * 64 + sl * 16;
  }
  #pragma unroll
  for (int n = 0; n < 6; ++n) {
    int r = wn * 96 + n * 16 + (lane & 15);
    int sl = (lane >> 4) ^ ((r >> 1) & 3);
    offB[n] = r * 64 + sl * 16;
  }

  stage(0, 0);
  for (int tk = 0; tk < NTK; ++tk) {
    int cur = tk & 1;
    __syncthreads();               // drains vmcnt(0): staged tile ready
    if (tk + 1 < NTK) stage(tk + 1, cur ^ 1);
    bf16x8 af[4], bfr[6];
    #pragma unroll
    for (int m = 0; m < 4; ++m) af[m] = *(const bf16x8*)(As[cur] + offA[m]);
    #pragma unroll
    for (int n = 0; n < 6; ++n) bfr[n] = *(const bf16x8*)(Bs[cur] + offB[n]);
    #pragma unroll
    for (int m = 0; m < 4; ++m)
      #pragma unroll
      for (int n = 0; n < 6; ++n)
        acc[m][n] = __builtin_amdgcn_mfma_f32_16x16x32_bf16(af[m], bfr[n], acc[m][n], 0, 0, 0);
  }

  // epilogue: sum of squares over this block's 96-col slice, reduce 16 lanes,
  // atomicAdd into norm2[row]  (C/D layout: col=lane&15, row=(lane>>4)*4+reg)
  float ps[4][4];
  #pragma unroll
  for (int m = 0; m < 4; ++m)
    #pragma unroll
    for (int i = 0; i < 4; ++i) {
      float v = 0.f;
      #pragma unroll
      for (int n = 0; n < 6; ++n) { float x = acc[m][n][i]; v += x * x; }
      #pragma unroll
      for (int d = 1; d < 16; d <<= 1) v += __shfl_xor(v, d, 64);
      ps[m][i] = v;
    }
  if ((lane & 15) == 0) {
    int g = lane >> 4;
    #pragma unroll
    for (int m = 0; m < 4; ++m)
      #pragma unroll
      for (int i = 0; i < 4; ++i)
        atomicAdd(&norm2[tm * BM + wm * 64 + m * 16 + g * 4 + i], ps[m][i]);
  }
}

// ---------------- kernel C: cv = relu(sqrt(norm2)*scale); shapley ------------
__global__ __launch_bounds__(128) void kC(const char* __restrict__ ws,
                                          const float* __restrict__ scale,
                                          float* __restrict__ out) {
  const int b = blockIdx.x, n = threadIdx.x;
  const float* norm2 = (const float*)(ws + OFF_N2);
  const float* coefT = (const float*)(ws + OFF_COEF);
  __shared__ float cvs[32];
  if (n < KMC) {
    float nv = norm2[b * KMC + n];
    cvs[n] = fmaxf(sqrtf(fmaxf(nv, 0.f)) * scale[0], 0.f);
  } else if (n < 32) {
    cvs[n] = 0.f;
  }
  __syncthreads();
  float sum = 0.f;
  #pragma unroll
  for (int k = 0; k < KMC; ++k) sum += cvs[k] * coefT[n * 28 + k];
  out[b * NSP + n] = sum;
}

extern "C" void kernel_launch(void* const* d_in, const int* in_sizes, int n_in,
                              void* d_out, int out_size, void* d_ws, size_t ws_size,
                              hipStream_t stream) {
  const float* features   = (const float*)d_in[0];
  const int*   coalitions = (const int*)d_in[1];
  const float* wv         = (const float*)d_in[2];
  const float* scale      = (const float*)d_in[3];
  char* ws = (char*)d_ws;

  prep_kernel<<<202, 256, 0, stream>>>(wv, coalitions, ws);
  dim3 gaa(NB, 2);
  // DIAGNOSTIC: kA launched twice (idempotent). total = C + kA_cold + kA_warm
  // discriminates {kA fixed + C small | kA still slow | C large}. Remove next round.
  kA<<<gaa, 512, 0, stream>>>(features, (const __hip_bfloat16*)(ws + OFF_CB),
                              (__hip_bfloat16*)(ws + OFF_S));
  kA<<<gaa, 512, 0, stream>>>(features, (const __hip_bfloat16*)(ws + OFF_CB),
                              (__hip_bfloat16*)(ws + OFF_S));
  kB<<<200, 256, 0, stream>>>(ws);
  kC<<<NB, 128, 0, stream>>>(ws, scale, (float*)d_out);
}

// Round 8
// 51.791 us; speedup vs baseline: 1.3906x; 1.3906x over previous
//
#include <hip/hip_runtime.h>
#include <hip/hip_bf16.h>
#include <stdint.h>

#define NB  256     // batch
#define NSP 128     // n_spins
#define DM  768     // d_model
#define KMC 25      // coalitions
#define MROWS (NB*KMC)  // 6400

// workspace layout (bytes), all 256-aligned (ws is 384 MiB)
#define OFF_S    0u          // s bf16 [6400][768]          9,830,400 B
#define OFF_WT   9830400u    // w_v^T bf16 [768][768]       1,179,648 B
#define OFF_N2   11010048u   // norm2 f32 [6400]               25,600 B
#define OFF_COEF 11035648u   // coefT f32 [128][28]            14,336 B
#define OFF_CB   11049984u   // Cb bf16 [32][128] (pad rows)    8,192 B

typedef __attribute__((ext_vector_type(8))) short bf16x8;
typedef __attribute__((ext_vector_type(4))) float f32x4;
typedef unsigned int u32;

#define GLOAD_LDS16(gp, lp) \
  __builtin_amdgcn_global_load_lds((const __attribute__((address_space(1))) u32*)(gp), \
                                   (__attribute__((address_space(3))) u32*)(lp), 16, 0, 0)

// lgkm-only barrier: LDS visibility without draining global loads (vmcnt
// stays counted -> prefetched chunks survive across the barrier). This is
// the T4 mechanism; __syncthreads() would emit vmcnt(0) and kill the pipe.
#define BARRIER_LGKM() do { \
    asm volatile("s_waitcnt lgkmcnt(0)" ::: "memory"); \
    __builtin_amdgcn_sched_barrier(0); \
    __builtin_amdgcn_s_barrier(); \
    __builtin_amdgcn_sched_barrier(0); \
  } while (0)

// ---------------- prep: transpose w_v -> bf16 wT, coef/C tables, zero norm2 -
__global__ __launch_bounds__(256) void prep_kernel(const float* __restrict__ wv,
                                                   const int* __restrict__ co,
                                                   char* __restrict__ ws) {
  const int blk = blockIdx.x;
  const int t = threadIdx.x;
  if (blk < 144) {               // 12x12 tiles of 64x64: wT[n][k] = bf16(wv[k][n])
    __shared__ __hip_bfloat16 lt[64][66];
    const int bi = blk / 12, bj = blk % 12;
    const int k0 = bi * 64, n0 = bj * 64;
    #pragma unroll
    for (int i = 0; i < 16; ++i) {
      int idx = t + i * 256;
      int r = idx >> 6, c = idx & 63;
      lt[c][r] = __float2bfloat16(wv[(size_t)(k0 + r) * DM + n0 + c]);
    }
    __syncthreads();
    __hip_bfloat16* wT = (__hip_bfloat16*)(ws + OFF_WT);
    #pragma unroll
    for (int i = 0; i < 16; ++i) {
      int idx = t + i * 256;
      int r = idx >> 6, c = idx & 63;
      wT[(size_t)(n0 + r) * DM + k0 + c] = lt[r][c];
    }
  } else if (blk == 144) {       // per-(n,k) shapley coefficients
    if (t < NSP) {
      const int n = t;
      int cw = 0;
      #pragma unroll
      for (int k = 0; k < KMC; ++k) cw += co[k * NSP + n];
      const int cwo = KMC - cw;
      const bool valid = (cw > 0) && (cwo > 0);
      float* coefT = (float*)(ws + OFF_COEF);
      #pragma unroll
      for (int k = 0; k < 28; ++k) {
        float v = 0.f;
        if (valid && k < KMC) v = co[k * NSP + n] ? (1.f / (float)cw) : (-1.f / (float)cwo);
        coefT[n * 28 + k] = v;
      }
    }
  } else if (blk < 170) {        // zero norm2 accumulators
    int i = (blk - 145) * 256 + t;
    if (i < MROWS) ((float*)(ws + OFF_N2))[i] = 0.f;
  } else {                       // blk 170..201: Cb row k (bf16, rows>=KMC zero)
    int k = blk - 170;
    if (t < NSP) {
      float v = (k < KMC) ? (float)co[k * NSP + t] : 0.f;
      ((__hip_bfloat16*)(ws + OFF_CB))[k * NSP + t] = __float2bfloat16(v);
    }
  }
}

// ---------------- kernel A: s[b] = C(25x128) x F_b(128x768) via bf16 MFMA ---
// 1 block/CU (grid 256 b x 2 halves, 512 thr = 8 waves, 48 cols/wave).
// F staged via regs (float4 loads issued a chunk early, ds_write_b64 late)
// into a double-buffered padded f32 slab [32][390] (frag reads 2-way-bank,
// free). Barriers are lgkm-only so prefetch loads stay in flight (T4).
#define KAPW 390            // padded slab row width (floats)
#define KASL (32 * KAPW)    // floats per buffer

__global__ __launch_bounds__(512, 2) void kA(const float* __restrict__ f,
                                             const __hip_bfloat16* __restrict__ Cb,
                                             __hip_bfloat16* __restrict__ s) {
  const int b = blockIdx.x;
  const int half = blockIdx.y;     // d-half: cols [half*384, half*384+384)
  const int tid = threadIdx.x;
  const int w = tid >> 6;          // 8 waves, 48 cols each
  const int lo = tid & 15, hi = (tid & 63) >> 4;

  __shared__ __align__(16) float Fs[2][KASL];   // 99,840 B

  // A-fragments (coalition rows), k = ks*32 + hi*8 + j (proven mapping)
  bf16x8 A0[4], A1[4];
  #pragma unroll
  for (int ks = 0; ks < 4; ++ks) {
    A0[ks] = *(const bf16x8*)(Cb + (size_t)lo * NSP + ks * 32 + hi * 8);
    A1[ks] = *(const bf16x8*)(Cb + (size_t)(16 + lo) * NSP + ks * 32 + hi * 8);
  }

  // per-thread staging geometry: 6 float4 per chunk, full-row coalesced
  int goff[6], waddr[6];
  #pragma unroll
  for (int p = 0; p < 6; ++p) {
    int e = 4 * tid + 2048 * p;        // float index into [32][384] slab
    int r = e / 384, c = e - r * 384;  // 4|e -> 4|c -> 16B global, 8B LDS align
    goff[p] = r * DM + c;
    waddr[p] = r * KAPW + c;
  }

  const float* fb = f + (size_t)b * NSP * DM + half * 384;

  f32x4 ac0[3], ac1[3];
  #pragma unroll
  for (int ct = 0; ct < 3; ++ct)
    #pragma unroll
    for (int i = 0; i < 4; ++i) { ac0[ct][i] = 0.f; ac1[ct][i] = 0.f; }

  float4 rA[6], rB[6];

#define KAL(chunk, reg) { \
    const float* fp_ = fb + (chunk) * 32 * DM; \
    _Pragma("unroll") for (int p = 0; p < 6; ++p) \
      reg[p] = *(const float4*)(fp_ + goff[p]); }

#define KAST(reg, bi) { \
    _Pragma("unroll") for (int p = 0; p < 6; ++p) { \
      *(float2*)(&Fs[bi][waddr[p]])     = make_float2(reg[p].x, reg[p].y); \
      *(float2*)(&Fs[bi][waddr[p] + 2]) = make_float2(reg[p].z, reg[p].w); } }

#define KAC(ks, bi) { \
    _Pragma("unroll") for (int ct = 0; ct < 3; ++ct) { \
      bf16x8 Bf; \
      _Pragma("unroll") for (int j = 0; j < 8; ++j) { \
        float v_ = Fs[bi][(hi * 8 + j) * KAPW + w * 48 + ct * 16 + lo]; \
        __hip_bfloat16 h_ = __float2bfloat16(v_); \
        Bf[j] = *(short*)&h_; } \
      ac0[ct] = __builtin_amdgcn_mfma_f32_16x16x32_bf16(A0[ks], Bf, ac0[ct], 0, 0, 0); \
      ac1[ct] = __builtin_amdgcn_mfma_f32_16x16x32_bf16(A1[ks], Bf, ac1[ct], 0, 0, 0); } }

  KAL(0, rA)
  KAL(1, rB)
  KAST(rA, 0)                    // compiler waits rA only (rB stays in flight)
  BARRIER_LGKM();

  KAC(0, 0)
  BARRIER_LGKM();
  KAL(2, rA)                     // issued before rB's wait; survives barriers
  KAST(rB, 1)
  BARRIER_LGKM();

  KAC(1, 1)
  BARRIER_LGKM();
  KAL(3, rB)
  KAST(rA, 0)
  BARRIER_LGKM();

  KAC(2, 0)
  BARRIER_LGKM();
  KAST(rB, 1)
  BARRIER_LGKM();

  KAC(3, 1)

#undef KAL
#undef KAST
#undef KAC

  // epilogue: D layout col=lane&15, row=(lane>>4)*4+i
  #pragma unroll
  for (int ct = 0; ct < 3; ++ct) {
    int dcol = half * 384 + w * 48 + ct * 16 + lo;
    #pragma unroll
    for (int i = 0; i < 4; ++i) {
      int r0 = hi * 4 + i;
      s[((size_t)b * KMC + r0) * DM + dcol] = __float2bfloat16(ac0[ct][i]);
      int r1 = 16 + hi * 4 + i;
      if (r1 < KMC)
        s[((size_t)b * KMC + r1) * DM + dcol] = __float2bfloat16(ac1[ct][i]);
    }
  }
}

// ---------------- kernel B: norm2[row] += rowwise |s @ wT^T|^2 (bf16 MFMA) ---
#define BM 128
#define BN 192
#define BK 32
#define NTK 24   // 768/32

__global__ __launch_bounds__(256) void kB(char* __restrict__ ws) {
  const int bid = blockIdx.x;      // grid 200 = 50 (M) * 4 (N)
  const int tm = bid >> 2;
  const int tn = bid & 3;
  const int tid = threadIdx.x;
  const int wid = tid >> 6;
  const int lane = tid & 63;
  const int wm = wid >> 1;         // 2x2 wave grid: 64 rows x 96 cols per wave
  const int wn = wid & 1;

  const __hip_bfloat16* S  = (const __hip_bfloat16*)(ws + OFF_S);
  const __hip_bfloat16* WT = (const __hip_bfloat16*)(ws + OFF_WT);
  float* norm2 = (float*)(ws + OFF_N2);

  __shared__ __align__(16) char As[2][BM * BK * 2];  // [128][32] bf16, 64B rows
  __shared__ __align__(16) char Bs[2][BN * BK * 2];  // [192][32] bf16, 64B rows

  // staging: global src pre-swizzled (slot ^= (r>>1)&3), LDS dest linear
  const char* gA[2]; char *lA0[2], *lA1[2];
  #pragma unroll
  for (int j = 0; j < 2; ++j) {
    int li = (wid * 2 + j) * 64 + lane;
    int r = li >> 2, sl = li & 3;
    int slx = sl ^ ((r >> 1) & 3);
    gA[j] = (const char*)(S + (size_t)(tm * BM + r) * DM) + slx * 16;
    lA0[j] = As[0] + (wid * 2 + j) * 1024;
    lA1[j] = As[1] + (wid * 2 + j) * 1024;
  }
  const char* gB[3]; char *lB0[3], *lB1[3];
  #pragma unroll
  for (int j = 0; j < 3; ++j) {
    int li = (wid * 3 + j) * 64 + lane;
    int r = li >> 2, sl = li & 3;
    int slx = sl ^ ((r >> 1) & 3);
    gB[j] = (const char*)(WT + (size_t)(tn * BN + r) * DM) + slx * 16;
    lB0[j] = Bs[0] + (wid * 3 + j) * 1024;
    lB1[j] = Bs[1] + (wid * 3 + j) * 1024;
  }

  auto stage = [&](int tk, int bsel) {
    size_t koff = (size_t)tk * (BK * 2);   // 64 bytes per K-step
    #pragma unroll
    for (int j = 0; j < 2; ++j) GLOAD_LDS16(gA[j] + koff, bsel ? lA1[j] : lA0[j]);
    #pragma unroll
    for (int j = 0; j < 3; ++j) GLOAD_LDS16(gB[j] + koff, bsel ? lB1[j] : lB0[j]);
  };

  f32x4 acc[4][6];
  #pragma unroll
  for (int m = 0; m < 4; ++m)
    #pragma unroll
    for (int n = 0; n < 6; ++n)
      #pragma unroll
      for (int j = 0; j < 4; ++j) acc[m][n][j] = 0.f;

  // fragment read offsets (swizzled to match stage-source permutation)
  int offA[4], offB[6];
  #pragma unroll
  for (int m = 0; m < 4; ++m) {
    int r = wm * 64 + m * 16 + (lane & 15);
    int sl = (lane >> 4) ^ ((r >> 1) & 3);
    offA[m] = r * 64 + sl * 16;
  }
  #pragma unroll
  for (int n = 0; n < 6; ++n) {
    int r = wn * 96 + n * 16 + (lane & 15);
    int sl = (lane >> 4) ^ ((r >> 1) & 3);
    offB[n] = r * 64 + sl * 16;
  }

  stage(0, 0);
  for (int tk = 0; tk < NTK; ++tk) {
    int cur = tk & 1;
    __syncthreads();               // drains vmcnt(0): staged tile ready
    if (tk + 1 < NTK) stage(tk + 1, cur ^ 1);
    bf16x8 af[4], bfr[6];
    #pragma unroll
    for (int m = 0; m < 4; ++m) af[m] = *(const bf16x8*)(As[cur] + offA[m]);
    #pragma unroll
    for (int n = 0; n < 6; ++n) bfr[n] = *(const bf16x8*)(Bs[cur] + offB[n]);
    #pragma unroll
    for (int m = 0; m < 4; ++m)
      #pragma unroll
      for (int n = 0; n < 6; ++n)
        acc[m][n] = __builtin_amdgcn_mfma_f32_16x16x32_bf16(af[m], bfr[n], acc[m][n], 0, 0, 0);
  }

  // epilogue: sum of squares over this block's 96-col slice, reduce 16 lanes,
  // atomicAdd into norm2[row]  (C/D layout: col=lane&15, row=(lane>>4)*4+reg)
  float ps[4][4];
  #pragma unroll
  for (int m = 0; m < 4; ++m)
    #pragma unroll
    for (int i = 0; i < 4; ++i) {
      float v = 0.f;
      #pragma unroll
      for (int n = 0; n < 6; ++n) { float x = acc[m][n][i]; v += x * x; }
      #pragma unroll
      for (int d = 1; d < 16; d <<= 1) v += __shfl_xor(v, d, 64);
      ps[m][i] = v;
    }
  if ((lane & 15) == 0) {
    int g = lane >> 4;
    #pragma unroll
    for (int m = 0; m < 4; ++m)
      #pragma unroll
      for (int i = 0; i < 4; ++i)
        atomicAdd(&norm2[tm * BM + wm * 64 + m * 16 + g * 4 + i], ps[m][i]);
  }
}

// ---------------- kernel C: cv = relu(sqrt(norm2)*scale); shapley ------------
__global__ __launch_bounds__(128) void kC(const char* __restrict__ ws,
                                          const float* __restrict__ scale,
                                          float* __restrict__ out) {
  const int b = blockIdx.x, n = threadIdx.x;
  const float* norm2 = (const float*)(ws + OFF_N2);
  const float* coefT = (const float*)(ws + OFF_COEF);
  __shared__ float cvs[32];
  if (n < KMC) {
    float nv = norm2[b * KMC + n];
    cvs[n] = fmaxf(sqrtf(fmaxf(nv, 0.f)) * scale[0], 0.f);
  } else if (n < 32) {
    cvs[n] = 0.f;
  }
  __syncthreads();
  float sum = 0.f;
  #pragma unroll
  for (int k = 0; k < KMC; ++k) sum += cvs[k] * coefT[n * 28 + k];
  out[b * NSP + n] = sum;
}

extern "C" void kernel_launch(void* const* d_in, const int* in_sizes, int n_in,
                              void* d_out, int out_size, void* d_ws, size_t ws_size,
                              hipStream_t stream) {
  const float* features   = (const float*)d_in[0];
  const int*   coalitions = (const int*)d_in[1];
  const float* wv         = (const float*)d_in[2];
  const float* scale      = (const float*)d_in[3];
  char* ws = (char*)d_ws;

  prep_kernel<<<202, 256, 0, stream>>>(wv, coalitions, ws);
  dim3 gaa(NB, 2);
  kA<<<gaa, 512, 0, stream>>>(features, (const __hip_bfloat16*)(ws + OFF_CB),
                              (__hip_bfloat16*)(ws + OFF_S));
  kB<<<200, 256, 0, stream>>>(ws);
  kC<<<NB, 128, 0, stream>>>(ws, scale, (float*)d_out);
}

// Round 9
// 49.619 us; speedup vs baseline: 1.4515x; 1.0438x over previous
//
#include <hip/hip_runtime.h>
#include <hip/hip_bf16.h>
#include <stdint.h>

#define NB  256     // batch
#define NSP 128     // n_spins
#define DM  768     // d_model
#define KMC 25      // coalitions
#define MROWS (NB*KMC)  // 6400

// workspace layout (bytes), all 256-aligned (ws is 384 MiB)
#define OFF_S    0u          // s bf16 [6400][768]          9,830,400 B
#define OFF_WT   9830400u    // w_v^T bf16 [768][768]       1,179,648 B
#define OFF_N2   11010048u   // norm2 f32 [6400]               25,600 B
#define OFF_COEF 11035648u   // coefT f32 [128][28]            14,336 B
#define OFF_CB   11049984u   // Cb bf16 [32][128] (pad rows)    8,192 B

typedef __attribute__((ext_vector_type(8))) short bf16x8;
typedef __attribute__((ext_vector_type(4))) float f32x4;
typedef unsigned int u32;

#define GLOAD_LDS16(gp, lp) \
  __builtin_amdgcn_global_load_lds((const __attribute__((address_space(1))) u32*)(gp), \
                                   (__attribute__((address_space(3))) u32*)(lp), 16, 0, 0)

// ---------------- prep: transpose w_v -> bf16 wT, coef/C tables, zero norm2 -
__global__ __launch_bounds__(256) void prep_kernel(const float* __restrict__ wv,
                                                   const int* __restrict__ co,
                                                   char* __restrict__ ws) {
  const int blk = blockIdx.x;
  const int t = threadIdx.x;
  if (blk < 144) {               // 12x12 tiles of 64x64: wT[n][k] = bf16(wv[k][n])
    __shared__ __hip_bfloat16 lt[64][66];
    const int bi = blk / 12, bj = blk % 12;
    const int k0 = bi * 64, n0 = bj * 64;
    #pragma unroll
    for (int i = 0; i < 16; ++i) {
      int idx = t + i * 256;
      int r = idx >> 6, c = idx & 63;
      lt[c][r] = __float2bfloat16(wv[(size_t)(k0 + r) * DM + n0 + c]);
    }
    __syncthreads();
    __hip_bfloat16* wT = (__hip_bfloat16*)(ws + OFF_WT);
    #pragma unroll
    for (int i = 0; i < 16; ++i) {
      int idx = t + i * 256;
      int r = idx >> 6, c = idx & 63;
      wT[(size_t)(n0 + r) * DM + k0 + c] = lt[r][c];
    }
  } else if (blk == 144) {       // per-(n,k) shapley coefficients
    if (t < NSP) {
      const int n = t;
      int cw = 0;
      #pragma unroll
      for (int k = 0; k < KMC; ++k) cw += co[k * NSP + n];
      const int cwo = KMC - cw;
      const bool valid = (cw > 0) && (cwo > 0);
      float* coefT = (float*)(ws + OFF_COEF);
      #pragma unroll
      for (int k = 0; k < 28; ++k) {
        float v = 0.f;
        if (valid && k < KMC) v = co[k * NSP + n] ? (1.f / (float)cw) : (-1.f / (float)cwo);
        coefT[n * 28 + k] = v;
      }
    }
  } else if (blk < 170) {        // zero norm2 accumulators
    int i = (blk - 145) * 256 + t;
    if (i < MROWS) ((float*)(ws + OFF_N2))[i] = 0.f;
  } else {                       // blk 170..201: Cb row k (bf16, rows>=KMC zero)
    int k = blk - 170;
    if (t < NSP) {
      float v = (k < KMC) ? (float)co[k * NSP + t] : 0.f;
      ((__hip_bfloat16*)(ws + OFF_CB))[k * NSP + t] = __float2bfloat16(v);
    }
  }
}

// ---------------- kernel A: s[b] = C(25x128) x F_b(128x768) via bf16 MFMA ---
// TLP-first design: 256-thr blocks (4 waves), grid 256 b x 4 slices (192 cols),
// bf16 LDS slab [2][32][196] = 25.1 KB -> 4 blocks/CU, 16 waves/CU. f32->bf16
// conversion happens during staging (cvt_pk + ds_write_b64); MFMA reads bf16
// directly. Simple serial chunk pipeline; block-level TLP hides HBM latency.
#define KBPW 196            // padded bf16 slab row width (2-way bank on reads)

__global__ __launch_bounds__(256, 4) void kA(const float* __restrict__ f,
                                             const __hip_bfloat16* __restrict__ Cb,
                                             __hip_bfloat16* __restrict__ s) {
  const int b = blockIdx.x;
  const int slice = blockIdx.y;    // 4 slices x 192 cols
  const int tid = threadIdx.x;
  const int w = tid >> 6;          // 4 waves, 48 cols each
  const int lane = tid & 63;
  const int lo = lane & 15, hi = lane >> 4;

  __shared__ __align__(16) unsigned short Fs[2][32 * KBPW];   // 25,088 B

  // A-fragments (coalition rows), k = ks*32 + hi*8 + j (proven mapping)
  bf16x8 A0[4], A1[4];
  #pragma unroll
  for (int ks = 0; ks < 4; ++ks) {
    A0[ks] = *(const bf16x8*)(Cb + (size_t)lo * NSP + ks * 32 + hi * 8);
    A1[ks] = *(const bf16x8*)(Cb + (size_t)(16 + lo) * NSP + ks * 32 + hi * 8);
  }

  // staging geometry: 6 float4 per thread per 32x192 chunk, row-coalesced
  int goff[6], waddr[6];
  #pragma unroll
  for (int p = 0; p < 6; ++p) {
    int e = 4 * tid + 1024 * p;        // float index into [32][192] chunk
    int r = e / 192, c = e - r * 192;  // 4|c -> 16B global align, 8B LDS align
    goff[p] = r * DM + c;
    waddr[p] = r * KBPW + c;
  }

  const float* fb = f + (size_t)b * NSP * DM + slice * 192;

  f32x4 ac0[3], ac1[3];
  #pragma unroll
  for (int ct = 0; ct < 3; ++ct)
    #pragma unroll
    for (int i = 0; i < 4; ++i) { ac0[ct][i] = 0.f; ac1[ct][i] = 0.f; }

  float4 rA[6];

#define KA_LOAD(ck) { \
    const float* fp_ = fb + (size_t)(ck) * 32 * DM; \
    _Pragma("unroll") for (int p = 0; p < 6; ++p) \
      rA[p] = *(const float4*)(fp_ + goff[p]); }

#define KA_STORE(bi) { \
    _Pragma("unroll") for (int p = 0; p < 6; ++p) { \
      __hip_bfloat16 h0_ = __float2bfloat16(rA[p].x); \
      __hip_bfloat16 h1_ = __float2bfloat16(rA[p].y); \
      __hip_bfloat16 h2_ = __float2bfloat16(rA[p].z); \
      __hip_bfloat16 h3_ = __float2bfloat16(rA[p].w); \
      u32 w0_ = (u32)*(unsigned short*)&h0_ | ((u32)*(unsigned short*)&h1_ << 16); \
      u32 w1_ = (u32)*(unsigned short*)&h2_ | ((u32)*(unsigned short*)&h3_ << 16); \
      u32* d_ = (u32*)&Fs[bi][waddr[p]]; \
      d_[0] = w0_; d_[1] = w1_; } }

#define KA_MFMA(ck, bi) { \
    _Pragma("unroll") for (int ct = 0; ct < 3; ++ct) { \
      bf16x8 Bf; \
      _Pragma("unroll") for (int j = 0; j < 8; ++j) \
        Bf[j] = (short)Fs[bi][(hi * 8 + j) * KBPW + w * 48 + ct * 16 + lo]; \
      ac0[ct] = __builtin_amdgcn_mfma_f32_16x16x32_bf16(A0[ck], Bf, ac0[ct], 0, 0, 0); \
      ac1[ct] = __builtin_amdgcn_mfma_f32_16x16x32_bf16(A1[ck], Bf, ac1[ct], 0, 0, 0); } }

  // chunk pipeline: issue next-chunk loads right after the barrier, before MFMA
  KA_LOAD(0)
  KA_STORE(0)
  __syncthreads();
  KA_LOAD(1)
  KA_MFMA(0, 0)
  KA_STORE(1)
  __syncthreads();
  KA_LOAD(2)
  KA_MFMA(1, 1)
  KA_STORE(0)
  __syncthreads();
  KA_LOAD(3)
  KA_MFMA(2, 0)
  KA_STORE(1)
  __syncthreads();
  KA_MFMA(3, 1)

#undef KA_LOAD
#undef KA_STORE
#undef KA_MFMA

  // epilogue: D layout col=lane&15, row=(lane>>4)*4+i
  #pragma unroll
  for (int ct = 0; ct < 3; ++ct) {
    int dcol = slice * 192 + w * 48 + ct * 16 + lo;
    #pragma unroll
    for (int i = 0; i < 4; ++i) {
      int r0 = hi * 4 + i;
      s[((size_t)b * KMC + r0) * DM + dcol] = __float2bfloat16(ac0[ct][i]);
      int r1 = 16 + hi * 4 + i;
      if (r1 < KMC)
        s[((size_t)b * KMC + r1) * DM + dcol] = __float2bfloat16(ac1[ct][i]);
    }
  }
}

// ---------------- kernel B: norm2[row] += rowwise |s @ wT^T|^2 (bf16 MFMA) ---
#define BM 128
#define BN 192
#define BK 32
#define NTK 24   // 768/32

__global__ __launch_bounds__(256) void kB(char* __restrict__ ws) {
  const int bid = blockIdx.x;      // grid 200 = 50 (M) * 4 (N)
  const int tm = bid >> 2;
  const int tn = bid & 3;
  const int tid = threadIdx.x;
  const int wid = tid >> 6;
  const int lane = tid & 63;
  const int wm = wid >> 1;         // 2x2 wave grid: 64 rows x 96 cols per wave
  const int wn = wid & 1;

  const __hip_bfloat16* S  = (const __hip_bfloat16*)(ws + OFF_S);
  const __hip_bfloat16* WT = (const __hip_bfloat16*)(ws + OFF_WT);
  float* norm2 = (float*)(ws + OFF_N2);

  __shared__ __align__(16) char As[2][BM * BK * 2];  // [128][32] bf16, 64B rows
  __shared__ __align__(16) char Bs[2][BN * BK * 2];  // [192][32] bf16, 64B rows

  // staging: global src pre-swizzled (slot ^= (r>>1)&3), LDS dest linear
  const char* gA[2]; char *lA0[2], *lA1[2];
  #pragma unroll
  for (int j = 0; j < 2; ++j) {
    int li = (wid * 2 + j) * 64 + lane;
    int r = li >> 2, sl = li & 3;
    int slx = sl ^ ((r >> 1) & 3);
    gA[j] = (const char*)(S + (size_t)(tm * BM + r) * DM) + slx * 16;
    lA0[j] = As[0] + (wid * 2 + j) * 1024;
    lA1[j] = As[1] + (wid * 2 + j) * 1024;
  }
  const char* gB[3]; char *lB0[3], *lB1[3];
  #pragma unroll
  for (int j = 0; j < 3; ++j) {
    int li = (wid * 3 + j) * 64 + lane;
    int r = li >> 2, sl = li & 3;
    int slx = sl ^ ((r >> 1) & 3);
    gB[j] = (const char*)(WT + (size_t)(tn * BN + r) * DM) + slx * 16;
    lB0[j] = Bs[0] + (wid * 3 + j) * 1024;
    lB1[j] = Bs[1] + (wid * 3 + j) * 1024;
  }

  auto stage = [&](int tk, int bsel) {
    size_t koff = (size_t)tk * (BK * 2);   // 64 bytes per K-step
    #pragma unroll
    for (int j = 0; j < 2; ++j) GLOAD_LDS16(gA[j] + koff, bsel ? lA1[j] : lA0[j]);
    #pragma unroll
    for (int j = 0; j < 3; ++j) GLOAD_LDS16(gB[j] + koff, bsel ? lB1[j] : lB0[j]);
  };

  f32x4 acc[4][6];
  #pragma unroll
  for (int m = 0; m < 4; ++m)
    #pragma unroll
    for (int n = 0; n < 6; ++n)
      #pragma unroll
      for (int j = 0; j < 4; ++j) acc[m][n][j] = 0.f;

  // fragment read offsets (swizzled to match stage-source permutation)
  int offA[4], offB[6];
  #pragma unroll
  for (int m = 0; m < 4; ++m) {
    int r = wm * 64 + m * 16 + (lane & 15);
    int sl = (lane >> 4) ^ ((r >> 1) & 3);
    offA[m] = r * 64 + sl * 16;
  }
  #pragma unroll
  for (int n = 0; n < 6; ++n) {
    int r = wn * 96 + n * 16 + (lane & 15);
    int sl = (lane >> 4) ^ ((r >> 1) & 3);
    offB[n] = r * 64 + sl * 16;
  }

  stage(0, 0);
  for (int tk = 0; tk < NTK; ++tk) {
    int cur = tk & 1;
    __syncthreads();               // drains vmcnt(0): staged tile ready
    if (tk + 1 < NTK) stage(tk + 1, cur ^ 1);
    bf16x8 af[4], bfr[6];
    #pragma unroll
    for (int m = 0; m < 4; ++m) af[m] = *(const bf16x8*)(As[cur] + offA[m]);
    #pragma unroll
    for (int n = 0; n < 6; ++n) bfr[n] = *(const bf16x8*)(Bs[cur] + offB[n]);
    #pragma unroll
    for (int m = 0; m < 4; ++m)
      #pragma unroll
      for (int n = 0; n < 6; ++n)
        acc[m][n] = __builtin_amdgcn_mfma_f32_16x16x32_bf16(af[m], bfr[n], acc[m][n], 0, 0, 0);
  }

  // epilogue: sum of squares over this block's 96-col slice, reduce 16 lanes,
  // atomicAdd into norm2[row]  (C/D layout: col=lane&15, row=(lane>>4)*4+reg)
  float ps[4][4];
  #pragma unroll
  for (int m = 0; m < 4; ++m)
    #pragma unroll
    for (int i = 0; i < 4; ++i) {
      float v = 0.f;
      #pragma unroll
      for (int n = 0; n < 6; ++n) { float x = acc[m][n][i]; v += x * x; }
      #pragma unroll
      for (int d = 1; d < 16; d <<= 1) v += __shfl_xor(v, d, 64);
      ps[m][i] = v;
    }
  if ((lane & 15) == 0) {
    int g = lane >> 4;
    #pragma unroll
    for (int m = 0; m < 4; ++m)
      #pragma unroll
      for (int i = 0; i < 4; ++i)
        atomicAdd(&norm2[tm * BM + wm * 64 + m * 16 + g * 4 + i], ps[m][i]);
  }
}

// ---------------- kernel C: cv = relu(sqrt(norm2)*scale); shapley ------------
__global__ __launch_bounds__(128) void kC(const char* __restrict__ ws,
                                          const float* __restrict__ scale,
                                          float* __restrict__ out) {
  const int b = blockIdx.x, n = threadIdx.x;
  const float* norm2 = (const float*)(ws + OFF_N2);
  const float* coefT = (const float*)(ws + OFF_COEF);
  __shared__ float cvs[32];
  if (n < KMC) {
    float nv = norm2[b * KMC + n];
    cvs[n] = fmaxf(sqrtf(fmaxf(nv, 0.f)) * scale[0], 0.f);
  } else if (n < 32) {
    cvs[n] = 0.f;
  }
  __syncthreads();
  float sum = 0.f;
  #pragma unroll
  for (int k = 0; k < KMC; ++k) sum += cvs[k] * coefT[n * 28 + k];
  out[b * NSP + n] = sum;
}

extern "C" void kernel_launch(void* const* d_in, const int* in_sizes, int n_in,
                              void* d_out, int out_size, void* d_ws, size_t ws_size,
                              hipStream_t stream) {
  const float* features   = (const float*)d_in[0];
  const int*   coalitions = (const int*)d_in[1];
  const float* wv         = (const float*)d_in[2];
  const float* scale      = (const float*)d_in[3];
  char* ws = (char*)d_ws;

  prep_kernel<<<202, 256, 0, stream>>>(wv, coalitions, ws);
  dim3 gaa(NB, 4);
  kA<<<gaa, 256, 0, stream>>>(features, (const __hip_bfloat16*)(ws + OFF_CB),
                              (__hip_bfloat16*)(ws + OFF_S));
  kB<<<200, 256, 0, stream>>>(ws);
  kC<<<NB, 128, 0, stream>>>(ws, scale, (float*)d_out);
}